// Round 5
// baseline (317.652 us; speedup 1.0000x reference)
//
#include <hip/hip_runtime.h>
#include <hip/hip_bf16.h>

// N=50000 nodes, E=800000 edges, D=96 (in = hidden = out)
#define NNODES 50000
#define NEDGES 800000
#define DIM    96
#define NBUCK  196      // ceil(N/256): bucket = dst >> 8
#define CAP    4608     // per-bucket capacity (mean 4096, sigma 64 -> +8 sigma)
#define TM     64       // rows per GEMM block
#define XPAD   104      // LDS row stride (bf16), 16B-aligned
#define PCH    3125     // edges per partition block (256 * 3125 = 800000)
#define GTS    50048    // transposed activation stride (nodes, padded to 64)
#define GHALF  25024    // half of GTS (one LDS stage = 48.9 KB)
#define ARC    5        // row chunks for k_aggr_t (grid = 96*5 = 480)
#define ACH    10000    // rows per chunk
#define ARPT   20       // rows per thread (ceil(10000/512))

typedef __attribute__((ext_vector_type(8))) short   short8;   // 8 bf16 = 4 VGPRs
typedef __attribute__((ext_vector_type(4))) short   short4v;  // 4 bf16 = 8B
typedef __attribute__((ext_vector_type(4))) float   float4v;  // MFMA acc

// flags[0] = 1 if float tensors are bf16, 0 if f32
// flags[1] = 1 if edge_index is int64, 0 if int32
__device__ __forceinline__ float loadF(const void* p, long i, int isbf) {
    return isbf ? __bfloat162float(((const __hip_bfloat16*)p)[i])
                : ((const float*)p)[i];
}
__device__ __forceinline__ int clampN(int v) {
    return v < 0 ? 0 : (v >= NNODES ? NNODES - 1 : v);
}
__device__ __forceinline__ int edgeDst(const int* w, int e, int is64) {
    return clampN(is64 ? w[2 * (NEDGES + e)] : w[NEDGES + e]);
}
__device__ __forceinline__ int edgeSrc(const int* w, int e, int is64) {
    return clampN(is64 ? w[2 * e] : w[e]);
}
__device__ __forceinline__ float bfbits2f(unsigned short u) {
    unsigned x = ((unsigned)u) << 16;
    return __uint_as_float(x);
}
__device__ __forceinline__ unsigned short f2bfbits(float f) {
    __hip_bfloat16 h = __float2bfloat16(f);
    return *(unsigned short*)&h;
}

// single wave: sniff dtypes; zero the per-bucket cursors (replaces memsets)
__global__ void k_sniff(const unsigned* __restrict__ xw,
                        const unsigned* __restrict__ ew,
                        int* __restrict__ flags,
                        int* __restrict__ bcur) {
    int lane = threadIdx.x;
    for (int i = lane; i < NBUCK; i += 64) bcur[i] = 0;
    int bad = 0, nz = 0;
    for (int r = 0; r < 4; ++r) {
        unsigned w  = xw[lane + 64 * r];
        unsigned lo = w & 0xffffu;
        unsigned ex = (lo >> 7) & 0xffu;
        if (!(lo == 0u || (ex >= 90u && ex <= 145u))) bad++;
        unsigned o = ew[2 * (lane + 64 * r) + 1];
        if (o != 0u) nz++;
    }
    for (int off = 32; off; off >>= 1) {
        bad += __shfl_down(bad, off);
        nz  += __shfl_down(nz,  off);
    }
    if (lane == 0) {
        flags[0] = (bad <= 32) ? 1 : 0;
        flags[1] = (nz  <  4) ? 1 : 0;
    }
}

// partition edges into FIXED-CAPACITY bucket regions: decode once into LDS,
// LDS histogram, reserve range via one atomicAdd on bcur, scatter from LDS.
__global__ __launch_bounds__(256) void k_part(const int* __restrict__ w,
                                              int* __restrict__ bcur,
                                              unsigned* __restrict__ ebuf,
                                              const int* __restrict__ flags) {
    __shared__ unsigned pack[PCH];   // 12.5 KB: this block's packed edges
    __shared__ int h[NBUCK];
    __shared__ int base[NBUCK];
    const int is64 = flags[1];
    const int tid  = threadIdx.x;
    const int e0   = blockIdx.x * PCH;

    for (int i = tid; i < NBUCK; i += 256) h[i] = 0;
    __syncthreads();
    for (int k = tid; k < PCH; k += 256) {
        int e = e0 + k;
        int s = edgeSrc(w, e, is64);
        int d = edgeDst(w, e, is64);
        pack[k] = ((unsigned)d << 16) | (unsigned)s;
        atomicAdd(&h[d >> 8], 1);
    }
    __syncthreads();
    for (int i = tid; i < NBUCK; i += 256) {
        int c = h[i];
        base[i] = c ? i * CAP + atomicAdd(&bcur[i], c) : 0;
        h[i] = 0;                    // reuse as local cursor
    }
    __syncthreads();
    for (int k = tid; k < PCH; k += 256) {
        unsigned r = pack[k];
        int b = r >> 24;             // dst >> 8
        int pos = base[b] + atomicAdd(&h[b], 1);
        if (pos < (b + 1) * CAP) ebuf[pos] = r;   // overflow guard (never hit)
    }
}

// per-bucket local CSR (512 threads): histogram 256 local dsts, scan ->
// rowbeg/rowmid/rowend/dinv in PADDED coordinates. Within each row the col
// entries are SPLIT: [beg,mid) has src < GHALF, [mid,end) has src >= GHALF
// (low half scatters forward, high half scatters backward).
__global__ __launch_bounds__(512) void k_csr(const unsigned* __restrict__ ebuf,
                                             const int* __restrict__ bcur,
                                             int* __restrict__ rowbeg,
                                             int* __restrict__ rowmid,
                                             int* __restrict__ rowend,
                                             unsigned short* __restrict__ col,
                                             float* __restrict__ dinv) {
    __shared__ int h256[256];
    __shared__ int sc[256];
    __shared__ int cur_lo[256];
    __shared__ int cur_hi[256];
    const int b   = blockIdx.x;
    const int tid = threadIdx.x;
    int cnt = bcur[b]; if (cnt > CAP) cnt = CAP;
    const int e0 = b * CAP;
    const int e1 = e0 + cnt;

    if (tid < 256) h256[tid] = 0;
    __syncthreads();
    for (int e = e0 + tid; e < e1; e += 512)
        atomicAdd(&h256[(ebuf[e] >> 16) & 255], 1);
    __syncthreads();
    int v = 0;
    if (tid < 256) { v = h256[tid]; sc[tid] = v; }
    __syncthreads();
    for (int off = 1; off < 256; off <<= 1) {
        int t2 = 0;
        if (tid < 256 && tid >= off) t2 = sc[tid - off];
        __syncthreads();
        if (tid < 256) sc[tid] += t2;
        __syncthreads();
    }
    if (tid < 256) {
        int start = e0 + sc[tid] - v;    // exclusive, padded coordinates
        cur_lo[tid] = start;
        cur_hi[tid] = start + v - 1;
        int node = b * 256 + tid;
        if (node < NNODES) {
            rowbeg[node] = start;
            rowend[node] = start + v;
            dinv[node] = rsqrtf((float)v + 1.0f);   // +1 self loop
        }
    }
    __syncthreads();
    for (int e = e0 + tid; e < e1; e += 512) {
        unsigned r = ebuf[e];
        int dl = (r >> 16) & 255;
        int s  = (int)(r & 0xffffu);
        int pos = (s < GHALF) ? atomicAdd(&cur_lo[dl], 1)
                              : atomicAdd(&cur_hi[dl], -1);
        col[pos] = (unsigned short)s;
    }
    __syncthreads();
    if (tid < 256) {
        int node = b * 256 + tid;
        if (node < NNODES) rowmid[node] = cur_lo[tid];
    }
}

// MFMA GEMM: g_t[n][row] = bf16( dinv[row] * (X[row,:] @ W)[n] ), TRANSPOSED
// output (stride GTS). xmode: 0 = row-major input (dtype per flags),
// 1 = transposed bf16 input (h_t from k_aggr_t).
__global__ __launch_bounds__(256) void k_gemm_mfma(
        const void* __restrict__ X, int xmode,
        const void* __restrict__ W,
        const float* __restrict__ dinv,
        unsigned short* __restrict__ gt,
        const int* __restrict__ flags) {
    __shared__ __hip_bfloat16 Xs[TM * XPAD];
    __shared__ __hip_bfloat16 Wt[DIM * XPAD];

    const int t    = threadIdx.x;
    const int fbf  = flags[0];
    const int row0 = blockIdx.x * TM;

    // stage W^T (vectorized when f32)
    if (!fbf) {
        const float4* Wv = (const float4*)W;
        for (int idx = t; idx < DIM * DIM / 4; idx += 256) {
            int k = idx / (DIM / 4);
            int n = (idx - k * (DIM / 4)) * 4;
            float4 w4 = Wv[idx];
            Wt[(n + 0) * XPAD + k] = __float2bfloat16(w4.x);
            Wt[(n + 1) * XPAD + k] = __float2bfloat16(w4.y);
            Wt[(n + 2) * XPAD + k] = __float2bfloat16(w4.z);
            Wt[(n + 3) * XPAD + k] = __float2bfloat16(w4.w);
        }
    } else {
        for (int idx = t; idx < DIM * DIM; idx += 256) {
            int k = idx / DIM, n = idx - k * DIM;
            Wt[n * XPAD + k] = __float2bfloat16(loadF(W, idx, 1));
        }
    }
    // stage X strip
    if (xmode == 1) {
        // transposed bf16 input: Xs[r][c] = ht[c*GTS + row0 + r]
        const unsigned short* ht = (const unsigned short*)X;
        short* xs = (short*)Xs;
        for (int idx = t; idx < DIM * 16; idx += 256) {
            int c  = idx >> 4;
            int sg = idx & 15;
            short4v v = *(const short4v*)(ht + (size_t)c * GTS + row0 + sg * 4);
            xs[(sg * 4 + 0) * XPAD + c] = v[0];
            xs[(sg * 4 + 1) * XPAD + c] = v[1];
            xs[(sg * 4 + 2) * XPAD + c] = v[2];
            xs[(sg * 4 + 3) * XPAD + c] = v[3];
        }
    } else if (!fbf) {
        const float4* Xv = (const float4*)X;
        for (int idx = t; idx < TM * (DIM / 4); idx += 256) {
            int r = idx / (DIM / 4);
            int c = (idx - r * (DIM / 4)) * 4;
            int gr = row0 + r;
            float4 vv = {0.f, 0.f, 0.f, 0.f};
            if (gr < NNODES) vv = Xv[(size_t)gr * (DIM / 4) + (c >> 2)];
            *(__hip_bfloat162*)&Xs[r * XPAD + c] =
                __halves2bfloat162(__float2bfloat16(vv.x), __float2bfloat16(vv.y));
            *(__hip_bfloat162*)&Xs[r * XPAD + c + 2] =
                __halves2bfloat162(__float2bfloat16(vv.z), __float2bfloat16(vv.w));
        }
    } else {
        const short* Xs16 = (const short*)X;
        for (int idx = t; idx < TM * (DIM / 8); idx += 256) {
            int r  = idx / (DIM / 8);
            int c8 = idx - r * (DIM / 8);
            int gr = row0 + r;
            short8 vv = {0, 0, 0, 0, 0, 0, 0, 0};
            if (gr < NNODES) vv = *(const short8*)(Xs16 + (size_t)gr * DIM + c8 * 8);
            *(short8*)((short*)Xs + r * XPAD + c8 * 8) = vv;
        }
    }
    __syncthreads();

    const int wave = t >> 6;
    const int lane = t & 63;
    const int m    = lane & 15;
    const int quad = lane >> 4;

    const short* xsp = (const short*)Xs;
    short8 a[3];
#pragma unroll
    for (int kt = 0; kt < 3; ++kt)
        a[kt] = *(const short8*)(xsp + (wave * 16 + m) * XPAD + kt * 32 + quad * 8);

    const int gr0 = row0 + wave * 16 + quad * 4;
    float dv[4];
#pragma unroll
    for (int r2 = 0; r2 < 4; ++r2)
        dv[r2] = (gr0 + r2 < NNODES) ? dinv[gr0 + r2] : 0.f;

    const short* wtp = (const short*)Wt;
#pragma unroll
    for (int nt = 0; nt < 6; ++nt) {
        float4v acc = {0.f, 0.f, 0.f, 0.f};
#pragma unroll
        for (int kt = 0; kt < 3; ++kt) {
            short8 b = *(const short8*)(wtp + (nt * 16 + m) * XPAD + kt * 32 + quad * 8);
            acc = __builtin_amdgcn_mfma_f32_16x16x32_bf16(a[kt], b, acc, 0, 0, 0);
        }
        // transposed write: 4 consecutive rows of column (nt*16+m) = one 8B store
        short4v o;
        o[0] = (short)f2bfbits(acc[0] * dv[0]);
        o[1] = (short)f2bfbits(acc[1] * dv[1]);
        o[2] = (short)f2bfbits(acc[2] * dv[2]);
        o[3] = (short)f2bfbits(acc[3] * dv[3]);
        *(short4v*)(gt + (size_t)(nt * 16 + m) * GTS + gr0) = o;
    }
}

// gather 8 neighbors (full or clamped/masked tail) from the LDS column table
__device__ __forceinline__ float gather8(const unsigned short* __restrict__ cb,
                                         const unsigned short* __restrict__ col,
                                         int j, int last, int sub) {
    int i0 = j     > last ? last : j;
    int i1 = j + 1 > last ? last : j + 1;
    int i2 = j + 2 > last ? last : j + 2;
    int i3 = j + 3 > last ? last : j + 3;
    int i4 = j + 4 > last ? last : j + 4;
    int i5 = j + 5 > last ? last : j + 5;
    int i6 = j + 6 > last ? last : j + 6;
    int i7 = j + 7 > last ? last : j + 7;
    int s0 = col[i0] - sub, s1 = col[i1] - sub, s2 = col[i2] - sub, s3 = col[i3] - sub;
    int s4 = col[i4] - sub, s5 = col[i5] - sub, s6 = col[i6] - sub, s7 = col[i7] - sub;
    float v0 = (j     <= last) ? bfbits2f(cb[s0]) : 0.f;
    float v1 = (j + 1 <= last) ? bfbits2f(cb[s1]) : 0.f;
    float v2 = (j + 2 <= last) ? bfbits2f(cb[s2]) : 0.f;
    float v3 = (j + 3 <= last) ? bfbits2f(cb[s3]) : 0.f;
    float v4 = (j + 4 <= last) ? bfbits2f(cb[s4]) : 0.f;
    float v5 = (j + 5 <= last) ? bfbits2f(cb[s5]) : 0.f;
    float v6 = (j + 6 <= last) ? bfbits2f(cb[s6]) : 0.f;
    float v7 = (j + 7 <= last) ? bfbits2f(cb[s7]) : 0.f;
    return ((v0 + v1) + (v2 + v3)) + ((v4 + v5) + (v6 + v7));
}

// transposed LDS-staged SpMM: block = (column c, row-chunk of 10000).
// Stage g_t[c][half] (48.9 KB) into LDS, accumulate per-thread rows from the
// half-split col lists, repeat for the other half, then epilogue
// (dinv * acc + bias, optional PReLU) with coalesced transposed stores.
__global__ __launch_bounds__(512, 4) void k_aggr_t(
        const unsigned short* __restrict__ gt,
        const int* __restrict__ rowbeg,
        const int* __restrict__ rowmid,
        const int* __restrict__ rowend,
        const unsigned short* __restrict__ col,
        const float* __restrict__ dinv,
        const void* __restrict__ b,
        const void* __restrict__ a1,
        void* __restrict__ outt,
        const int* __restrict__ flags, int prelu) {
    __shared__ unsigned short cb[GHALF];   // 48.9 KB column half-table
    const int tid   = threadIdx.x;
    const int c     = blockIdx.x % DIM;
    const int rbase = (blockIdx.x / DIM) * ACH;
    const int fbf   = flags[0];
    const size_t cg = (size_t)c * GTS;

    float acc[ARPT];
#pragma unroll
    for (int r = 0; r < ARPT; ++r) acc[r] = 0.f;

    // ---- half 0: nodes [0, GHALF) ----
    {
        const uint4* src = (const uint4*)(gt + cg);
        for (int i = tid; i < GHALF / 8; i += 512) ((uint4*)cb)[i] = src[i];
    }
    __syncthreads();
#pragma unroll
    for (int r = 0; r < ARPT; ++r) {
        if (tid + r * 512 < ACH) {
            int row = rbase + tid + r * 512;
            int j = rowbeg[row], je = rowmid[row];
            float a = 0.f;
            while (j + 8 <= je) { a += gather8(cb, col, j, je - 1, 0); j += 8; }
            if (j < je)          a += gather8(cb, col, j, je - 1, 0);
            if (row < GHALF) a += bfbits2f(cb[row]);         // self loop
            acc[r] += a;
        }
    }
    __syncthreads();
    // ---- half 1: nodes [GHALF, GTS) ----
    {
        const uint4* src = (const uint4*)(gt + cg + GHALF);
        for (int i = tid; i < GHALF / 8; i += 512) ((uint4*)cb)[i] = src[i];
    }
    __syncthreads();
#pragma unroll
    for (int r = 0; r < ARPT; ++r) {
        if (tid + r * 512 < ACH) {
            int row = rbase + tid + r * 512;
            int j = rowmid[row], je = rowend[row];
            float a = 0.f;
            while (j + 8 <= je) { a += gather8(cb, col, j, je - 1, GHALF); j += 8; }
            if (j < je)          a += gather8(cb, col, j, je - 1, GHALF);
            if (row >= GHALF) a += bfbits2f(cb[row - GHALF]); // self loop
            acc[r] += a;
        }
    }

    // ---- epilogue ----
    const float bias  = loadF(b, c, fbf);
    const float alpha = prelu ? loadF(a1, 0, fbf) : 0.f;
#pragma unroll
    for (int r = 0; r < ARPT; ++r) {
        if (tid + r * 512 < ACH) {
            int row = rbase + tid + r * 512;
            float v = dinv[row] * acc[r] + bias;
            if (prelu) v = v > 0.f ? v : alpha * v;
            if (prelu || fbf)
                ((unsigned short*)outt)[cg + row] = f2bfbits(v);
            else
                ((float*)outt)[cg + row] = v;
        }
    }
}

// transpose o_t[c][row] -> row-major out[row][c] via LDS tiles of 64 rows
__global__ __launch_bounds__(256) void k_trans(const void* __restrict__ ot,
                                               void* __restrict__ out,
                                               const int* __restrict__ flags) {
    __shared__ __align__(16) char tbuf[DIM * 66 * 4];
    const int fbf = flags[0];
    const int t   = threadIdx.x;
    const int r0  = blockIdx.x * 64;
    const int r   = t >> 2;
    const int q   = t & 3;

    if (fbf) {
        unsigned short (*tile)[68] = (unsigned short(*)[68])tbuf;
        const unsigned short* src = (const unsigned short*)ot;
        for (int idx = t; idx < DIM * 16; idx += 256) {
            int c = idx >> 4, sg = idx & 15;
            short4v v = *(const short4v*)(src + (size_t)c * GTS + r0 + sg * 4);
            tile[c][sg * 4 + 0] = (unsigned short)v[0];
            tile[c][sg * 4 + 1] = (unsigned short)v[1];
            tile[c][sg * 4 + 2] = (unsigned short)v[2];
            tile[c][sg * 4 + 3] = (unsigned short)v[3];
        }
        __syncthreads();
        if (r0 + r < NNODES) {
            short8 w0, w1, w2;
#pragma unroll
            for (int k = 0; k < 8; ++k) {
                w0[k] = (short)tile[q * 24 + k][r];
                w1[k] = (short)tile[q * 24 + 8 + k][r];
                w2[k] = (short)tile[q * 24 + 16 + k][r];
            }
            unsigned short* dst = (unsigned short*)out + (size_t)(r0 + r) * DIM + q * 24;
            *(short8*)(dst)      = w0;
            *(short8*)(dst + 8)  = w1;
            *(short8*)(dst + 16) = w2;
        }
    } else {
        float (*tf)[66] = (float(*)[66])tbuf;
        const float* src = (const float*)ot;
        for (int idx = t; idx < DIM * 16; idx += 256) {
            int c = idx >> 4, sg = idx & 15;
            float4 v = *(const float4*)(src + (size_t)c * GTS + r0 + sg * 4);
            tf[c][sg * 4 + 0] = v.x;
            tf[c][sg * 4 + 1] = v.y;
            tf[c][sg * 4 + 2] = v.z;
            tf[c][sg * 4 + 3] = v.w;
        }
        __syncthreads();
        if (r0 + r < NNODES) {
            float* dst = (float*)out + (size_t)(r0 + r) * DIM + q * 24;
#pragma unroll
            for (int k6 = 0; k6 < 6; ++k6) {
                float4 v;
                v.x = tf[q * 24 + k6 * 4 + 0][r];
                v.y = tf[q * 24 + k6 * 4 + 1][r];
                v.z = tf[q * 24 + k6 * 4 + 2][r];
                v.w = tf[q * 24 + k6 * 4 + 3][r];
                *(float4*)(dst + k6 * 4) = v;
            }
        }
    }
}

extern "C" void kernel_launch(void* const* d_in, const int* in_sizes, int n_in,
                              void* d_out, int out_size, void* d_ws, size_t ws_size,
                              hipStream_t stream) {
    const void* x  = d_in[0];
    const int*  ei = (const int*)d_in[1];
    const void* W1 = d_in[2];
    const void* b1 = d_in[3];
    const void* a1 = d_in[4];
    const void* W2 = d_in[5];
    const void* b2 = d_in[6];

    size_t off = 0;
    auto alloc = [&](size_t bytes) { size_t p = off; off = (off + bytes + 255) & ~(size_t)255; return p; };
    char* ws = (char*)d_ws;
    int*            flags  = (int*)           (ws + alloc(1024));
    float*          dinv   = (float*)         (ws + alloc((size_t)NNODES * 4));
    int*            bcur   = (int*)           (ws + alloc((size_t)NBUCK * 4));
    int*            rowbeg = (int*)           (ws + alloc((size_t)NNODES * 4));
    int*            rowmid = (int*)           (ws + alloc((size_t)NNODES * 4));
    int*            rowend = (int*)           (ws + alloc((size_t)NNODES * 4));
    unsigned*       ebuf   = (unsigned*)      (ws + alloc((size_t)NBUCK * CAP * 4));
    unsigned short* col    = (unsigned short*)(ws + alloc((size_t)NBUCK * CAP * 2 + 256));
    unsigned short* gt     = (unsigned short*)(ws + alloc((size_t)DIM * GTS * 2));
    unsigned short* ht     = (unsigned short*)(ws + alloc((size_t)DIM * GTS * 2));
    void*           ot     = (void*)          (ws + alloc((size_t)DIM * GTS * 4));
    if (ws_size < off) return;   // ~45 MiB (workspace is ~256 MiB)

    // ---- CSR build: padded-bucket counting sort, half-split col lists ----
    k_sniff<<<1, 64, 0, stream>>>((const unsigned*)x, (const unsigned*)ei, flags, bcur);
    k_part <<<256, 256, 0, stream>>>(ei, bcur, ebuf, flags);
    k_csr  <<<NBUCK, 512, 0, stream>>>(ebuf, bcur, rowbeg, rowmid, rowend, col, dinv);

    const int gemm_grid = (NNODES + TM - 1) / TM;       // 782
    const int aggr_grid = DIM * ARC;                    // 480

    // ---- layer 1: GEMM (transposed out) + LDS-staged transposed SpMM ----
    k_gemm_mfma<<<gemm_grid, 256, 0, stream>>>(x, 0, W1, dinv, gt, flags);
    k_aggr_t<<<aggr_grid, 512, 0, stream>>>(gt, rowbeg, rowmid, rowend, col,
                                            dinv, b1, a1, ht, flags, 1);
    // ---- layer 2 ----
    k_gemm_mfma<<<gemm_grid, 256, 0, stream>>>(ht, 1, W2, dinv, gt, flags);
    k_aggr_t<<<aggr_grid, 512, 0, stream>>>(gt, rowbeg, rowmid, rowend, col,
                                            dinv, b2, a1, ot, flags, 0);
    // ---- transpose to row-major output ----
    k_trans<<<gemm_grid, 256, 0, stream>>>(ot, d_out, flags);
}

// Round 6
// 210.010 us; speedup vs baseline: 1.5126x; 1.5126x over previous
//
#include <hip/hip_runtime.h>
#include <hip/hip_bf16.h>

// N=50000 nodes, E=800000 edges, D=96 (in = hidden = out)
#define NNODES 50000
#define NEDGES 800000
#define DIM    96
#define NBUCK  196      // ceil(N/256): bucket = dst >> 8
#define CAP    4608     // per-bucket capacity (mean 4096, sigma 64 -> +8 sigma)
#define TM     64       // rows per GEMM block
#define XPAD   104      // LDS row stride (bf16), 16B-aligned
#define PCH    3125     // edges per partition block (256 * 3125 = 800000)
#define VLY    32       // gather volley width (P[deg>32] ~ 4e-4 of rows)

typedef __attribute__((ext_vector_type(8))) short   short8;   // 8 bf16 = 4 VGPRs
typedef __attribute__((ext_vector_type(4))) float   float4v;  // MFMA acc

// flags[0] = 1 if float tensors are bf16, 0 if f32
// flags[1] = 1 if edge_index is int64, 0 if int32
__device__ __forceinline__ float loadF(const void* p, long i, int isbf) {
    return isbf ? __bfloat162float(((const __hip_bfloat16*)p)[i])
                : ((const float*)p)[i];
}
__device__ __forceinline__ int clampN(int v) {
    return v < 0 ? 0 : (v >= NNODES ? NNODES - 1 : v);
}
__device__ __forceinline__ int edgeDst(const int* w, int e, int is64) {
    return clampN(is64 ? w[2 * (NEDGES + e)] : w[NEDGES + e]);
}
__device__ __forceinline__ int edgeSrc(const int* w, int e, int is64) {
    return clampN(is64 ? w[2 * e] : w[e]);
}

// single wave: sniff dtypes; zero the per-bucket cursors (replaces memsets)
__global__ void k_sniff(const unsigned* __restrict__ xw,
                        const unsigned* __restrict__ ew,
                        int* __restrict__ flags,
                        int* __restrict__ bcur) {
    int lane = threadIdx.x;
    for (int i = lane; i < NBUCK; i += 64) bcur[i] = 0;
    int bad = 0, nz = 0;
    for (int r = 0; r < 4; ++r) {
        unsigned w  = xw[lane + 64 * r];
        unsigned lo = w & 0xffffu;
        unsigned ex = (lo >> 7) & 0xffu;
        if (!(lo == 0u || (ex >= 90u && ex <= 145u))) bad++;
        unsigned o = ew[2 * (lane + 64 * r) + 1];
        if (o != 0u) nz++;
    }
    for (int off = 32; off; off >>= 1) {
        bad += __shfl_down(bad, off);
        nz  += __shfl_down(nz,  off);
    }
    if (lane == 0) {
        flags[0] = (bad <= 32) ? 1 : 0;
        flags[1] = (nz  <  4) ? 1 : 0;
    }
}

// partition edges into FIXED-CAPACITY bucket regions (no counting pass, no
// scan): decode once into LDS, LDS histogram, reserve [base, base+c) in the
// bucket's padded region via one atomicAdd on bcur, scatter from LDS.
__global__ __launch_bounds__(256) void k_part(const int* __restrict__ w,
                                              int* __restrict__ bcur,
                                              unsigned* __restrict__ ebuf,
                                              const int* __restrict__ flags) {
    __shared__ unsigned pack[PCH];   // 12.5 KB: this block's packed edges
    __shared__ int h[NBUCK];
    __shared__ int base[NBUCK];
    const int is64 = flags[1];
    const int tid  = threadIdx.x;
    const int e0   = blockIdx.x * PCH;

    for (int i = tid; i < NBUCK; i += 256) h[i] = 0;
    __syncthreads();
    for (int k = tid; k < PCH; k += 256) {
        int e = e0 + k;
        int s = edgeSrc(w, e, is64);
        int d = edgeDst(w, e, is64);
        pack[k] = ((unsigned)d << 16) | (unsigned)s;
        atomicAdd(&h[d >> 8], 1);
    }
    __syncthreads();
    for (int i = tid; i < NBUCK; i += 256) {
        int c = h[i];
        base[i] = c ? i * CAP + atomicAdd(&bcur[i], c) : 0;
        h[i] = 0;                    // reuse as local cursor
    }
    __syncthreads();
    for (int k = tid; k < PCH; k += 256) {
        unsigned r = pack[k];
        int b = r >> 24;             // dst >> 8
        int pos = base[b] + atomicAdd(&h[b], 1);
        if (pos < (b + 1) * CAP) ebuf[pos] = r;   // overflow guard (never hit)
    }
}

// per-bucket local CSR (512 threads): histogram 256 local dsts, scan ->
// rowbeg/rowend/dinv in PADDED coordinates, LDS-cursor scatter of col (u16).
__global__ __launch_bounds__(512) void k_csr(const unsigned* __restrict__ ebuf,
                                             const int* __restrict__ bcur,
                                             int* __restrict__ rowbeg,
                                             int* __restrict__ rowend,
                                             unsigned short* __restrict__ col,
                                             float* __restrict__ dinv) {
    __shared__ int h256[256];
    __shared__ int sc[256];
    __shared__ int cur[256];
    const int b   = blockIdx.x;
    const int tid = threadIdx.x;
    int cnt = bcur[b]; if (cnt > CAP) cnt = CAP;
    const int e0 = b * CAP;
    const int e1 = e0 + cnt;

    if (tid < 256) h256[tid] = 0;
    __syncthreads();
    for (int e = e0 + tid; e < e1; e += 512)
        atomicAdd(&h256[(ebuf[e] >> 16) & 255], 1);
    __syncthreads();
    int v = 0;
    if (tid < 256) { v = h256[tid]; sc[tid] = v; }
    __syncthreads();
    for (int off = 1; off < 256; off <<= 1) {
        int t2 = 0;
        if (tid < 256 && tid >= off) t2 = sc[tid - off];
        __syncthreads();
        if (tid < 256) sc[tid] += t2;
        __syncthreads();
    }
    if (tid < 256) {
        int start = e0 + sc[tid] - v;    // exclusive, padded coordinates
        cur[tid] = start;
        int node = b * 256 + tid;
        if (node < NNODES) {
            rowbeg[node] = start;
            rowend[node] = start + v;
            dinv[node] = rsqrtf((float)v + 1.0f);   // +1 self loop
        }
    }
    __syncthreads();
    for (int e = e0 + tid; e < e1; e += 512) {
        unsigned r = ebuf[e];
        int pos = atomicAdd(&cur[(r >> 16) & 255], 1);
        col[pos] = (unsigned short)(r & 0xffffu);
    }
}

// MFMA GEMM: g[row,:] = bf16( dinv[row] * (X[row,:] @ W) )
// block = 256 (4 waves), 64 rows/block; X strip + W^T staged in LDS as bf16.
__global__ __launch_bounds__(256) void k_gemm_mfma(
        const void* __restrict__ X, int x_force_bf16,
        const void* __restrict__ W,
        const float* __restrict__ dinv,
        __hip_bfloat16* __restrict__ g,
        const int* __restrict__ flags) {
    __shared__ __hip_bfloat16 Xs[TM * XPAD];
    __shared__ __hip_bfloat16 Wt[DIM * XPAD];

    const int t    = threadIdx.x;
    const int fbf  = flags[0];
    const int xbf  = x_force_bf16 ? 1 : fbf;
    const int row0 = blockIdx.x * TM;

    // stage W^T (vectorized when f32)
    if (!fbf) {
        const float4* Wv = (const float4*)W;
        for (int idx = t; idx < DIM * DIM / 4; idx += 256) {
            int k = idx / (DIM / 4);
            int n = (idx - k * (DIM / 4)) * 4;
            float4 w4 = Wv[idx];
            Wt[(n + 0) * XPAD + k] = __float2bfloat16(w4.x);
            Wt[(n + 1) * XPAD + k] = __float2bfloat16(w4.y);
            Wt[(n + 2) * XPAD + k] = __float2bfloat16(w4.z);
            Wt[(n + 3) * XPAD + k] = __float2bfloat16(w4.w);
        }
    } else {
        for (int idx = t; idx < DIM * DIM; idx += 256) {
            int k = idx / DIM, n = idx - k * DIM;
            Wt[n * XPAD + k] = __float2bfloat16(loadF(W, idx, 1));
        }
    }
    // stage X strip (vectorized both paths)
    if (!xbf) {
        const float4* Xv = (const float4*)X;
        for (int idx = t; idx < TM * (DIM / 4); idx += 256) {
            int r = idx / (DIM / 4);
            int c = (idx - r * (DIM / 4)) * 4;
            int gr = row0 + r;
            float4 vv = {0.f, 0.f, 0.f, 0.f};
            if (gr < NNODES) vv = Xv[(size_t)gr * (DIM / 4) + (c >> 2)];
            *(__hip_bfloat162*)&Xs[r * XPAD + c] =
                __halves2bfloat162(__float2bfloat16(vv.x), __float2bfloat16(vv.y));
            *(__hip_bfloat162*)&Xs[r * XPAD + c + 2] =
                __halves2bfloat162(__float2bfloat16(vv.z), __float2bfloat16(vv.w));
        }
    } else {
        const short* Xs16 = (const short*)X;
        for (int idx = t; idx < TM * (DIM / 8); idx += 256) {
            int r  = idx / (DIM / 8);
            int c8 = idx - r * (DIM / 8);
            int gr = row0 + r;
            short8 vv = {0, 0, 0, 0, 0, 0, 0, 0};
            if (gr < NNODES) vv = *(const short8*)(Xs16 + (size_t)gr * DIM + c8 * 8);
            *(short8*)((short*)Xs + r * XPAD + c8 * 8) = vv;
        }
    }
    __syncthreads();

    const int wave = t >> 6;
    const int lane = t & 63;
    const int m    = lane & 15;
    const int quad = lane >> 4;

    const short* xsp = (const short*)Xs;
    short8 a[3];
#pragma unroll
    for (int kt = 0; kt < 3; ++kt)
        a[kt] = *(const short8*)(xsp + (wave * 16 + m) * XPAD + kt * 32 + quad * 8);

    float dv[4];
#pragma unroll
    for (int r2 = 0; r2 < 4; ++r2) {
        int gr = row0 + wave * 16 + quad * 4 + r2;
        dv[r2] = (gr < NNODES) ? dinv[gr] : 0.f;
    }

    const short* wtp = (const short*)Wt;
#pragma unroll
    for (int nt = 0; nt < 6; ++nt) {
        float4v acc = {0.f, 0.f, 0.f, 0.f};
#pragma unroll
        for (int kt = 0; kt < 3; ++kt) {
            short8 b = *(const short8*)(wtp + (nt * 16 + m) * XPAD + kt * 32 + quad * 8);
            acc = __builtin_amdgcn_mfma_f32_16x16x32_bf16(a[kt], b, acc, 0, 0, 0);
        }
#pragma unroll
        for (int r2 = 0; r2 < 4; ++r2) {
            int gr = row0 + wave * 16 + quad * 4 + r2;
            if (gr < NNODES)
                g[(size_t)gr * DIM + nt * 16 + m] = __float2bfloat16(acc[r2] * dv[r2]);
        }
    }
}

// aggregate + epilogue: ONE WAVE per destination row, lanes 0..47 hold
// bfloat162 column pairs. ONE predicated 32-wide gather volley per row
// (covers 99.96% of Poisson(16) rows in a single vmcnt drain): clamped
// duplicate indices are L1 hits; lanes beyond deg masked by 0/1 multiply.
// __launch_bounds__(256,4) raises the VGPR cap to 128 so all 32 float2
// values stay in flight (the round-3 version register-minimized to 24 VGPR
// and serialized the volley into ~6-deep groups -> 2-3 serial miss chains).
__global__ __launch_bounds__(256, 4) void k_aggr(
        const __hip_bfloat16* __restrict__ g,
        const int* __restrict__ rowbeg,
        const int* __restrict__ rowend,
        const unsigned short* __restrict__ col,
        const float* __restrict__ dinv,
        const void* __restrict__ b,
        const void* __restrict__ a1,
        void* __restrict__ out,
        const int* __restrict__ flags, int prelu) {
    const int wave = threadIdx.x >> 6;
    const int lane = threadIdx.x & 63;
    const int row  = blockIdx.x * 4 + wave;
    if (row >= NNODES) return;                       // wave-uniform
    const int fbf = flags[0];
    const __hip_bfloat162* gv = (const __hip_bfloat162*)g;
    const int c = lane;                              // 0..47 active

    float2 acc = {0.f, 0.f};
    if (c < 48) acc = __bfloat1622float2(gv[(size_t)row * 48 + c]);  // self loop

    const int p0 = rowbeg[row], p1 = rowend[row];
    const int last = (p1 > p0) ? (p1 - 1) : p0;

    int s[VLY];
#pragma unroll
    for (int k = 0; k < VLY; ++k) {
        int idx = p0 + k;
        s[k] = col[idx > last ? last : idx];
    }
    if (c < 48) {
        float2 v[VLY];
#pragma unroll
        for (int k = 0; k < VLY; ++k)
            v[k] = __bfloat1622float2(gv[(size_t)s[k] * 48 + c]);
#pragma unroll
        for (int k = 0; k < VLY; ++k) {
            float m = (p0 + k < p1) ? 1.f : 0.f;
            acc.x += m * v[k].x;
            acc.y += m * v[k].y;
        }
    }
    // rare tail: deg > VLY (P ~ 4e-4)
    for (int i = p0 + VLY; i < p1; ++i) {
        int si = col[i];
        if (c < 48) {
            float2 v = __bfloat1622float2(gv[(size_t)si * 48 + c]);
            acc.x += v.x; acc.y += v.y;
        }
    }

    if (c < 48) {
        float dv = dinv[row];
        float vx = dv * acc.x + loadF(b, 2 * c,     fbf);
        float vy = dv * acc.y + loadF(b, 2 * c + 1, fbf);
        if (prelu) {
            float alpha = loadF(a1, 0, fbf);
            vx = vx > 0.f ? vx : alpha * vx;
            vy = vy > 0.f ? vy : alpha * vy;
            ((__hip_bfloat162*)out)[(size_t)row * 48 + c] =
                __halves2bfloat162(__float2bfloat16(vx), __float2bfloat16(vy));
        } else if (fbf) {
            ((__hip_bfloat162*)out)[(size_t)row * 48 + c] =
                __halves2bfloat162(__float2bfloat16(vx), __float2bfloat16(vy));
        } else {
            float2 o; o.x = vx; o.y = vy;
            ((float2*)out)[(size_t)row * 48 + c] = o;
        }
    }
}

extern "C" void kernel_launch(void* const* d_in, const int* in_sizes, int n_in,
                              void* d_out, int out_size, void* d_ws, size_t ws_size,
                              hipStream_t stream) {
    const void* x  = d_in[0];
    const int*  ei = (const int*)d_in[1];
    const void* W1 = d_in[2];
    const void* b1 = d_in[3];
    const void* a1 = d_in[4];
    const void* W2 = d_in[5];
    const void* b2 = d_in[6];

    size_t off = 0;
    auto alloc = [&](size_t bytes) { size_t p = off; off = (off + bytes + 255) & ~(size_t)255; return p; };
    char* ws = (char*)d_ws;
    int*            flags  = (int*)           (ws + alloc(1024));
    float*          dinv   = (float*)         (ws + alloc((size_t)NNODES * 4));
    int*            bcur   = (int*)           (ws + alloc((size_t)NBUCK * 4));
    int*            rowbeg = (int*)           (ws + alloc((size_t)NNODES * 4));
    int*            rowend = (int*)           (ws + alloc((size_t)NNODES * 4));
    unsigned*       ebuf   = (unsigned*)      (ws + alloc((size_t)NBUCK * CAP * 4));
    unsigned short* col    = (unsigned short*)(ws + alloc((size_t)NBUCK * CAP * 2 + 256));
    __hip_bfloat16* g      = (__hip_bfloat16*)(ws + alloc((size_t)NNODES * DIM * 2));
    __hip_bfloat16* g2     = (__hip_bfloat16*)(ws + alloc((size_t)NNODES * DIM * 2));
    if (ws_size < off) return;   // ~25.5 MiB

    // ---- CSR build: padded-bucket counting sort, single edge pass --------
    k_sniff<<<1, 64, 0, stream>>>((const unsigned*)x, (const unsigned*)ei, flags, bcur);
    k_part <<<256, 256, 0, stream>>>(ei, bcur, ebuf, flags);
    k_csr  <<<NBUCK, 512, 0, stream>>>(ebuf, bcur, rowbeg, rowend, col, dinv);

    const int gemm_grid = (NNODES + TM - 1) / TM;       // 782
    const int aggr_grid = (NNODES + 3) / 4;             // 12500 (4 rows/block)

    // ---- layer 1 ----
    k_gemm_mfma<<<gemm_grid, 256, 0, stream>>>(x, 0, W1, dinv, g, flags);
    k_aggr<<<aggr_grid, 256, 0, stream>>>(g, rowbeg, rowend, col, dinv, b1, a1, g2, flags, 1);

    // ---- layer 2 ----
    k_gemm_mfma<<<gemm_grid, 256, 0, stream>>>(g2, 1, W2, dinv, g, flags);
    k_aggr<<<aggr_grid, 256, 0, stream>>>(g, rowbeg, rowend, col, dinv, b2, a1, d_out, flags, 0);
}

// Round 8
// 192.287 us; speedup vs baseline: 1.6520x; 1.0922x over previous
//
#include <hip/hip_runtime.h>
#include <hip/hip_bf16.h>

// N=50000 nodes, E=800000 edges, D=96 (in = hidden = out)
#define NNODES 50000
#define NEDGES 800000
#define DIM    96
#define NBUCK  196      // ceil(N/256): bucket = dst >> 8
#define CAP    4608     // per-bucket col capacity (mean 4096, sigma 64 -> +8 sigma)
#define TM     64       // rows per GEMM block
#define XPAD   104      // LDS row stride (bf16), 16B-aligned
#define PCH    3125     // edges per partition chunk (256 * 3125 = 800000)
#define NCHK   256      // number of chunks
#define HP     256      // hist/hoff row stride (ints)

typedef __attribute__((ext_vector_type(8))) short   short8;   // 8 bf16 = 4 VGPRs
typedef __attribute__((ext_vector_type(4))) float   float4v;  // MFMA acc

// flags[0] = 1 if float tensors are bf16, 0 if f32
// flags[1] = 1 if edge_index is int64, 0 if int32
__device__ __forceinline__ float loadF(const void* p, long i, int isbf) {
    return isbf ? __bfloat162float(((const __hip_bfloat16*)p)[i])
                : ((const float*)p)[i];
}
__device__ __forceinline__ int clampN(int v) {
    return v < 0 ? 0 : (v >= NNODES ? NNODES - 1 : v);
}

// single wave: device-side dtype sniff (in_sizes are ELEMENT COUNTS host-side
// and cannot disambiguate dtype -- bit patterns can).
__global__ void k_sniff(const unsigned* __restrict__ xw,
                        const unsigned* __restrict__ ew,
                        int* __restrict__ flags) {
    int lane = threadIdx.x;
    int bad = 0, nz = 0;
    for (int r = 0; r < 4; ++r) {
        unsigned w  = xw[lane + 64 * r];
        unsigned lo = w & 0xffffu;
        unsigned ex = (lo >> 7) & 0xffu;
        if (!(lo == 0u || (ex >= 90u && ex <= 145u))) bad++;
        unsigned o = ew[2 * (lane + 64 * r) + 1];
        if (o != 0u) nz++;
    }
    for (int off = 32; off; off >>= 1) {
        bad += __shfl_down(bad, off);
        nz  += __shfl_down(nz,  off);
    }
    if (lane == 0) {
        flags[0] = (bad <= 32) ? 1 : 0;
        flags[1] = (nz  <  4) ? 1 : 0;
    }
}

// deterministic bucket-grouping partition: each block decodes its 3125-edge
// chunk, groups it by dst-bucket ENTIRELY IN LDS (histogram + scan + local
// scatter), writes the grouped chunk back contiguously (coalesced) plus the
// per-chunk (count, offset) tables. No global atomics, no grid sync.
__global__ __launch_bounds__(256) void k_part(const int* __restrict__ w,
                                              const int* __restrict__ flags,
                                              int* __restrict__ hist,
                                              int* __restrict__ hoff,
                                              unsigned* __restrict__ ebuf) {
    __shared__ unsigned pack[PCH];    // 12.5 KB raw decode
    __shared__ unsigned opack[PCH];   // 12.5 KB bucket-grouped
    __shared__ int h[256];
    __shared__ int sc[256];
    const int is64 = flags[1];
    const int tid = threadIdx.x;
    const int blk = blockIdx.x;
    const int e0  = blk * PCH;

    h[tid] = 0;
    __syncthreads();
    if (is64) {
        const long long* wl = (const long long*)w;
        for (int k = tid; k < PCH; k += 256) {
            int s = clampN((int)wl[e0 + k]);
            int d = clampN((int)wl[NEDGES + e0 + k]);
            pack[k] = ((unsigned)d << 16) | (unsigned)s;
            atomicAdd(&h[d >> 8], 1);
        }
    } else {
        for (int k = tid; k < PCH; k += 256) {
            int s = clampN(w[e0 + k]);
            int d = clampN(w[NEDGES + e0 + k]);
            pack[k] = ((unsigned)d << 16) | (unsigned)s;
            atomicAdd(&h[d >> 8], 1);
        }
    }
    __syncthreads();
    int v = h[tid];
    sc[tid] = v;
    __syncthreads();
    for (int off = 1; off < 256; off <<= 1) {
        int t2 = (tid >= off) ? sc[tid - off] : 0;
        __syncthreads();
        sc[tid] += t2;
        __syncthreads();
    }
    const int excl = sc[tid] - v;          // in-chunk exclusive bucket offset
    hist[blk * HP + tid] = v;
    hoff[blk * HP + tid] = excl;
    h[tid] = excl;                         // reuse as local cursor
    __syncthreads();
    for (int k = tid; k < PCH; k += 256) {
        unsigned r = pack[k];
        int pos = atomicAdd(&h[(r >> 16) >> 8], 1);   // LDS atomic
        opack[pos] = r;
    }
    __syncthreads();
    for (int k = tid; k < PCH; k += 256)   // coalesced writeback
        ebuf[e0 + k] = opack[k];
}

// per-bucket local CSR (512 threads, 196 blocks): thread-pairs walk the 256
// per-chunk slices of this bucket; histogram 256 local dsts, scan ->
// rowbeg/rowend/dinv in PADDED col coordinates, LDS-cursor scatter (u16).
__global__ __launch_bounds__(512) void k_csr(const unsigned* __restrict__ ebuf,
                                             const int* __restrict__ hist,
                                             const int* __restrict__ hoff,
                                             int* __restrict__ rowbeg,
                                             int* __restrict__ rowend,
                                             unsigned short* __restrict__ col,
                                             float* __restrict__ dinv) {
    __shared__ int h256[256];
    __shared__ int sc[256];
    __shared__ int cur[256];
    __shared__ int scnt[256];
    __shared__ int soff[256];
    const int b   = blockIdx.x;
    const int tid = threadIdx.x;

    if (tid < 256) {
        scnt[tid] = hist[tid * HP + b];
        soff[tid] = hoff[tid * HP + b];
        h256[tid] = 0;
    }
    __syncthreads();
    const int ch  = tid >> 1;          // chunk 0..255
    const int par = tid & 1;
    {
        const int cnt = scnt[ch];
        const int off = ch * PCH + soff[ch];
        for (int j = par; j < cnt; j += 2)
            atomicAdd(&h256[(ebuf[off + j] >> 16) & 255], 1);
    }
    __syncthreads();
    int v = 0;
    if (tid < 256) { v = h256[tid]; sc[tid] = v; }
    __syncthreads();
    for (int off = 1; off < 256; off <<= 1) {
        int t2 = 0;
        if (tid < 256 && tid >= off) t2 = sc[tid - off];
        __syncthreads();
        if (tid < 256) sc[tid] += t2;
        __syncthreads();
    }
    if (tid < 256) {
        int start = b * CAP + sc[tid] - v;   // exclusive, padded coordinates
        cur[tid] = start;
        int node = b * 256 + tid;
        if (node < NNODES) {
            rowbeg[node] = start;
            rowend[node] = start + v;
            dinv[node] = rsqrtf((float)v + 1.0f);   // +1 self loop
        }
    }
    __syncthreads();
    {
        const int cnt = scnt[ch];
        const int off = ch * PCH + soff[ch];
        const int lim = (b + 1) * CAP;
        for (int j = par; j < cnt; j += 2) {
            unsigned r = ebuf[off + j];
            int pos = atomicAdd(&cur[(r >> 16) & 255], 1);
            if (pos < lim) col[pos] = (unsigned short)(r & 0xffffu);
        }
    }
}

// MFMA GEMM: g[row,:] = bf16( dinv[row] * (X[row,:] @ W) )
// block = 256 (4 waves), 64 rows/block; X strip + W^T staged in LDS as bf16.
__global__ __launch_bounds__(256) void k_gemm_mfma(
        const void* __restrict__ X, int x_force_bf16,
        const void* __restrict__ W,
        const float* __restrict__ dinv,
        __hip_bfloat16* __restrict__ g,
        const int* __restrict__ flags) {
    __shared__ __hip_bfloat16 Xs[TM * XPAD];
    __shared__ __hip_bfloat16 Wt[DIM * XPAD];

    const int t    = threadIdx.x;
    const int fbf  = flags[0];
    const int xbf  = x_force_bf16 ? 1 : fbf;
    const int row0 = blockIdx.x * TM;

    // stage W^T (vectorized when f32)
    if (!fbf) {
        const float4* Wv = (const float4*)W;
        for (int idx = t; idx < DIM * DIM / 4; idx += 256) {
            int k = idx / (DIM / 4);
            int n = (idx - k * (DIM / 4)) * 4;
            float4 w4 = Wv[idx];
            Wt[(n + 0) * XPAD + k] = __float2bfloat16(w4.x);
            Wt[(n + 1) * XPAD + k] = __float2bfloat16(w4.y);
            Wt[(n + 2) * XPAD + k] = __float2bfloat16(w4.z);
            Wt[(n + 3) * XPAD + k] = __float2bfloat16(w4.w);
        }
    } else {
        for (int idx = t; idx < DIM * DIM; idx += 256) {
            int k = idx / DIM, n = idx - k * DIM;
            Wt[n * XPAD + k] = __float2bfloat16(loadF(W, idx, 1));
        }
    }
    // stage X strip (vectorized both paths)
    if (!xbf) {
        const float4* Xv = (const float4*)X;
        for (int idx = t; idx < TM * (DIM / 4); idx += 256) {
            int r = idx / (DIM / 4);
            int c = (idx - r * (DIM / 4)) * 4;
            int gr = row0 + r;
            float4 vv = {0.f, 0.f, 0.f, 0.f};
            if (gr < NNODES) vv = Xv[(size_t)gr * (DIM / 4) + (c >> 2)];
            *(__hip_bfloat162*)&Xs[r * XPAD + c] =
                __halves2bfloat162(__float2bfloat16(vv.x), __float2bfloat16(vv.y));
            *(__hip_bfloat162*)&Xs[r * XPAD + c + 2] =
                __halves2bfloat162(__float2bfloat16(vv.z), __float2bfloat16(vv.w));
        }
    } else {
        const short* Xs16 = (const short*)X;
        for (int idx = t; idx < TM * (DIM / 8); idx += 256) {
            int r  = idx / (DIM / 8);
            int c8 = idx - r * (DIM / 8);
            int gr = row0 + r;
            short8 vv = {0, 0, 0, 0, 0, 0, 0, 0};
            if (gr < NNODES) vv = *(const short8*)(Xs16 + (size_t)gr * DIM + c8 * 8);
            *(short8*)((short*)Xs + r * XPAD + c8 * 8) = vv;
        }
    }
    __syncthreads();

    const int wave = t >> 6;
    const int lane = t & 63;
    const int m    = lane & 15;
    const int quad = lane >> 4;

    const short* xsp = (const short*)Xs;
    short8 a[3];
#pragma unroll
    for (int kt = 0; kt < 3; ++kt)
        a[kt] = *(const short8*)(xsp + (wave * 16 + m) * XPAD + kt * 32 + quad * 8);

    float dv[4];
#pragma unroll
    for (int r2 = 0; r2 < 4; ++r2) {
        int gr = row0 + wave * 16 + quad * 4 + r2;
        dv[r2] = (gr < NNODES) ? dinv[gr] : 0.f;
    }

    const short* wtp = (const short*)Wt;
#pragma unroll
    for (int nt = 0; nt < 6; ++nt) {
        float4v acc = {0.f, 0.f, 0.f, 0.f};
#pragma unroll
        for (int kt = 0; kt < 3; ++kt) {
            short8 b = *(const short8*)(wtp + (nt * 16 + m) * XPAD + kt * 32 + quad * 8);
            acc = __builtin_amdgcn_mfma_f32_16x16x32_bf16(a[kt], b, acc, 0, 0, 0);
        }
#pragma unroll
        for (int r2 = 0; r2 < 4; ++r2) {
            int gr = row0 + wave * 16 + quad * 4 + r2;
            if (gr < NNODES)
                g[(size_t)gr * DIM + nt * 16 + m] = __float2bfloat16(acc[r2] * dv[r2]);
        }
    }
}

// aggregate + epilogue: ONE WAVE per destination row, lanes 0..47 hold
// bfloat162 column pairs (one gather instruction = one 192B row).
// Full 16-wide gather blocks + ONE predicated 16-wide tail block (clamped
// index -> duplicate loads are L1 hits, lanes beyond deg zeroed).
// Default regalloc (~24 VGPR) -> max occupancy; TLP hides miss latency.
__global__ __launch_bounds__(256) void k_aggr(
        const __hip_bfloat16* __restrict__ g,
        const int* __restrict__ rowbeg,
        const int* __restrict__ rowend,
        const unsigned short* __restrict__ col,
        const float* __restrict__ dinv,
        const void* __restrict__ b,
        const void* __restrict__ a1,
        void* __restrict__ out,
        const int* __restrict__ flags, int prelu) {
    const int wave = threadIdx.x >> 6;
    const int lane = threadIdx.x & 63;
    const int row  = blockIdx.x * 4 + wave;
    if (row >= NNODES) return;                       // wave-uniform
    const int fbf = flags[0];
    const __hip_bfloat162* gv = (const __hip_bfloat162*)g;
    const int c = lane;                              // 0..47 active

    float2 acc = {0.f, 0.f};
    if (c < 48) acc = __bfloat1622float2(gv[(size_t)row * 48 + c]);  // self loop

    const int p0 = rowbeg[row], p1 = rowend[row];
    int i = p0;
    for (; i + 16 <= p1; i += 16) {                  // full blocks
        int s[16];
#pragma unroll
        for (int k = 0; k < 16; ++k) s[k] = col[i + k];
        if (c < 48) {
            float2 v[16];
#pragma unroll
            for (int k = 0; k < 16; ++k)
                v[k] = __bfloat1622float2(gv[(size_t)s[k] * 48 + c]);
            float2 t0, t1, t2, t3;
            t0.x = (v[0].x + v[1].x) + (v[2].x + v[3].x);
            t0.y = (v[0].y + v[1].y) + (v[2].y + v[3].y);
            t1.x = (v[4].x + v[5].x) + (v[6].x + v[7].x);
            t1.y = (v[4].y + v[5].y) + (v[6].y + v[7].y);
            t2.x = (v[8].x + v[9].x) + (v[10].x + v[11].x);
            t2.y = (v[8].y + v[9].y) + (v[10].y + v[11].y);
            t3.x = (v[12].x + v[13].x) + (v[14].x + v[15].x);
            t3.y = (v[12].y + v[13].y) + (v[14].y + v[15].y);
            acc.x += (t0.x + t1.x) + (t2.x + t3.x);
            acc.y += (t0.y + t1.y) + (t2.y + t3.y);
        }
    }
    if (i < p1) {                                    // predicated tail block
        const int last = p1 - 1;
        int s[16];
#pragma unroll
        for (int k = 0; k < 16; ++k) {
            int idx = i + k;
            s[k] = col[idx > last ? last : idx];
        }
        if (c < 48) {
            float2 v[16];
#pragma unroll
            for (int k = 0; k < 16; ++k) {
                v[k] = __bfloat1622float2(gv[(size_t)s[k] * 48 + c]);
                if (i + k > last) { v[k].x = 0.f; v[k].y = 0.f; }
            }
            float2 t0, t1, t2, t3;
            t0.x = (v[0].x + v[1].x) + (v[2].x + v[3].x);
            t0.y = (v[0].y + v[1].y) + (v[2].y + v[3].y);
            t1.x = (v[4].x + v[5].x) + (v[6].x + v[7].x);
            t1.y = (v[4].y + v[5].y) + (v[6].y + v[7].y);
            t2.x = (v[8].x + v[9].x) + (v[10].x + v[11].x);
            t2.y = (v[8].y + v[9].y) + (v[10].y + v[11].y);
            t3.x = (v[12].x + v[13].x) + (v[14].x + v[15].x);
            t3.y = (v[12].y + v[13].y) + (v[14].y + v[15].y);
            acc.x += (t0.x + t1.x) + (t2.x + t3.x);
            acc.y += (t0.y + t1.y) + (t2.y + t3.y);
        }
    }

    if (c < 48) {
        float dv = dinv[row];
        float vx = dv * acc.x + loadF(b, 2 * c,     fbf);
        float vy = dv * acc.y + loadF(b, 2 * c + 1, fbf);
        if (prelu) {
            float alpha = loadF(a1, 0, fbf);
            vx = vx > 0.f ? vx : alpha * vx;
            vy = vy > 0.f ? vy : alpha * vy;
            ((__hip_bfloat162*)out)[(size_t)row * 48 + c] =
                __halves2bfloat162(__float2bfloat16(vx), __float2bfloat16(vy));
        } else if (fbf) {
            ((__hip_bfloat162*)out)[(size_t)row * 48 + c] =
                __halves2bfloat162(__float2bfloat16(vx), __float2bfloat16(vy));
        } else {
            float2 o; o.x = vx; o.y = vy;
            ((float2*)out)[(size_t)row * 48 + c] = o;
        }
    }
}

extern "C" void kernel_launch(void* const* d_in, const int* in_sizes, int n_in,
                              void* d_out, int out_size, void* d_ws, size_t ws_size,
                              hipStream_t stream) {
    const void* x  = d_in[0];
    const int*  ei = (const int*)d_in[1];
    const void* W1 = d_in[2];
    const void* b1 = d_in[3];
    const void* a1 = d_in[4];
    const void* W2 = d_in[5];
    const void* b2 = d_in[6];

    size_t off = 0;
    auto alloc = [&](size_t bytes) { size_t p = off; off = (off + bytes + 255) & ~(size_t)255; return p; };
    char* ws = (char*)d_ws;
    int*            flags  = (int*)           (ws + alloc(1024));
    float*          dinv   = (float*)         (ws + alloc((size_t)NNODES * 4));
    int*            rowbeg = (int*)           (ws + alloc((size_t)NNODES * 4));
    int*            rowend = (int*)           (ws + alloc((size_t)NNODES * 4));
    int*            hist   = (int*)           (ws + alloc((size_t)NCHK * HP * 4));
    int*            hoff   = (int*)           (ws + alloc((size_t)NCHK * HP * 4));
    unsigned*       ebuf   = (unsigned*)      (ws + alloc((size_t)NEDGES * 4));
    unsigned short* col    = (unsigned short*)(ws + alloc((size_t)NBUCK * CAP * 2 + 256));
    __hip_bfloat16* g      = (__hip_bfloat16*)(ws + alloc((size_t)NNODES * DIM * 2));
    __hip_bfloat16* g2     = (__hip_bfloat16*)(ws + alloc((size_t)NNODES * DIM * 2));
    if (ws_size < off) return;   // ~27 MiB

    // ---- CSR build: device sniff + deterministic LDS-grouped counting sort
    k_sniff<<<1, 64, 0, stream>>>((const unsigned*)x, (const unsigned*)ei, flags);
    k_part <<<NCHK, 256, 0, stream>>>(ei, flags, hist, hoff, ebuf);
    k_csr  <<<NBUCK, 512, 0, stream>>>(ebuf, hist, hoff, rowbeg, rowend, col, dinv);

    const int gemm_grid = (NNODES + TM - 1) / TM;       // 782
    const int aggr_grid = (NNODES + 3) / 4;             // 12500 (4 rows/block)

    // ---- layer 1 ----
    k_gemm_mfma<<<gemm_grid, 256, 0, stream>>>(x, 0, W1, dinv, g, flags);
    k_aggr<<<aggr_grid, 256, 0, stream>>>(g, rowbeg, rowend, col, dinv, b1, a1, g2, flags, 1);

    // ---- layer 2 ----
    k_gemm_mfma<<<gemm_grid, 256, 0, stream>>>(g2, 1, W2, dinv, g, flags);
    k_aggr<<<aggr_grid, 256, 0, stream>>>(g, rowbeg, rowend, col, dinv, b2, a1, d_out, flags, 0);
}